// Round 3
// baseline (784.786 us; speedup 1.0000x reference)
//
#include <hip/hip_runtime.h>
#include <hip/hip_bf16.h>

// Problem constants
#define B_SZ   64
#define N_IN   1024
#define D_IN   512
#define NC     32
#define DC     64
#define M_TOT  (B_SZ * N_IN)       // 65536
#define N_TOT  (NC * DC)           // 2048
#define K_TOT  D_IN                // 512

typedef __bf16 bf16x8 __attribute__((ext_vector_type(8)));
typedef float  f32x4  __attribute__((ext_vector_type(4)));
typedef unsigned short u16x8 __attribute__((ext_vector_type(8)));

__device__ __forceinline__ float bf2f(unsigned short u) {
    unsigned x = ((unsigned)u) << 16;
    return __builtin_bit_cast(float, x);
}
__device__ __forceinline__ unsigned short f2bf(float f) {
    unsigned x = __builtin_bit_cast(unsigned, f);
    unsigned r = (x + 0x7fffu + ((x >> 16) & 1u)) >> 16;   // RNE
    return (unsigned short)r;
}

#define ASYNC_LDS16(g, l) __builtin_amdgcn_global_load_lds( \
    (const __attribute__((address_space(1))) void*)(g),     \
    (__attribute__((address_space(3))) void*)(l), 16, 0, 0)

// ---------------------------------------------------------------------------
// A convert: fp32 [65536][512] -> bf16 (ushort) same layout.
// ---------------------------------------------------------------------------
__global__ __launch_bounds__(256) void convert_a(const float* __restrict__ in,
                                                 unsigned short* __restrict__ out) {
    size_t idx = ((size_t)blockIdx.x * 256 + threadIdx.x) * 8;
    float4 v0 = *(const float4*)(in + idx);
    float4 v1 = *(const float4*)(in + idx + 4);
    u16x8 r;
    r[0] = f2bf(v0.x); r[1] = f2bf(v0.y); r[2] = f2bf(v0.z); r[3] = f2bf(v0.w);
    r[4] = f2bf(v1.x); r[5] = f2bf(v1.y); r[6] = f2bf(v1.z); r[7] = f2bf(v1.w);
    *(u16x8*)(out + idx) = r;
}

// ---------------------------------------------------------------------------
// W transpose+convert: W fp32 [512][2048] -> Wt bf16 [2048][512]
// ---------------------------------------------------------------------------
__global__ __launch_bounds__(256) void transpose_w(const float* __restrict__ W,
                                                   unsigned short* __restrict__ Wt) {
    __shared__ unsigned short tile[32][33];
    const int n0 = blockIdx.x * 32;   // over N=2048
    const int k0 = blockIdx.y * 32;   // over K=512
    const int c  = threadIdx.x & 31;
    const int r4 = threadIdx.x >> 5;  // 0..7
    for (int it = 0; it < 4; ++it) {
        int r = it * 8 + r4;
        tile[r][c] = f2bf(W[(size_t)(k0 + r) * 2048 + n0 + c]);
    }
    __syncthreads();
    for (int it = 0; it < 4; ++it) {
        int r = it * 8 + r4;
        Wt[(size_t)(n0 + r) * 512 + k0 + c] = tile[c][r];
    }
}

// ---------------------------------------------------------------------------
// GEMM: u_hat[M=65536][N=2048] = A[M][K=512] * Wt[N][K]^T  (bf16 in, bf16 out)
// 128x128 tile, 4 waves (2x2 of 64x64), BK=64, 16x16x32 bf16 MFMA.
// LDS layout [row][64] (no padding -- global_load_lds is lane-ordered);
// bank aliasing broken by XOR-swizzling the 16B k-chunk with (row&7).
// ---------------------------------------------------------------------------
__global__ __launch_bounds__(256, 2) void gemm_kernel(const unsigned short* __restrict__ A,
                                                      const unsigned short* __restrict__ Bt,
                                                      unsigned short* __restrict__ Chat) {
    __shared__ unsigned short As[128 * 64];
    __shared__ unsigned short Bs[128 * 64];
    const int tid  = threadIdx.x;
    const int wid  = tid >> 6;
    const int lane = tid & 63;
    const int m0 = blockIdx.x * 128;   // 512 blocks
    const int n0 = blockIdx.y * 128;   // 16 blocks
    const int wrow = (wid >> 1) * 64;
    const int wcol = (wid & 1) * 64;

    const int lr = lane >> 3;                      // row within wave chunk (0..7)
    const int lc = ((lane & 7) ^ (lr & 7)) * 8;    // swizzled global k-chunk offset

    f32x4 acc[4][4] = {};

    const int quad = lane >> 4;
    const int l16  = lane & 15;

    for (int kt = 0; kt < 8; ++kt) {
        const int k0 = kt * 64;
        for (int iss = 0; iss < 4; ++iss) {
            const int rowbase = iss * 32 + wid * 8;
            const unsigned short* ga = A  + (size_t)(m0 + rowbase + lr) * 512 + k0 + lc;
            ASYNC_LDS16(ga, &As[rowbase * 64]);
            const unsigned short* gb = Bt + (size_t)(n0 + rowbase + lr) * 512 + k0 + lc;
            ASYNC_LDS16(gb, &Bs[rowbase * 64]);
        }
        __syncthreads();
        for (int kc = 0; kc < 2; ++kc) {
            const int C = kc * 4 + quad;           // global 16B-chunk index within BK
            bf16x8 af[4], bfr[4];
            for (int i = 0; i < 4; ++i) {
                int R = wrow + i * 16 + l16;
                af[i] = *(const bf16x8*)&As[R * 64 + ((C ^ (R & 7)) << 3)];
            }
            for (int j = 0; j < 4; ++j) {
                int R = wcol + j * 16 + l16;
                bfr[j] = *(const bf16x8*)&Bs[R * 64 + ((C ^ (R & 7)) << 3)];
            }
            for (int i = 0; i < 4; ++i)
                for (int j = 0; j < 4; ++j)
                    acc[i][j] = __builtin_amdgcn_mfma_f32_16x16x32_bf16(af[i], bfr[j], acc[i][j], 0, 0, 0);
        }
        __syncthreads();
    }

    // epilogue: D row = quad*4 + r, col = lane&15
    const int cm = quad * 4;
    for (int i = 0; i < 4; ++i)
        for (int j = 0; j < 4; ++j) {
            size_t base = (size_t)(m0 + wrow + i * 16 + cm) * 2048 + (n0 + wcol + j * 16 + l16);
            for (int r = 0; r < 4; ++r)
                Chat[base + (size_t)r * 2048] = f2bf(acc[i][j][r]);
        }
}

// ---------------------------------------------------------------------------
// accum: s[b][n][d] += sum_i c[b,n,i] * u_hat[b,i,n*64+d]
// c = softmax over n of logits[b][i][n]  (or uniform 1/32 on iteration 0)
// ---------------------------------------------------------------------------
__global__ __launch_bounds__(256) void accum_kernel(const unsigned short* __restrict__ u_hat,
                                                    const float* __restrict__ logits,
                                                    float* __restrict__ s, int uniform) {
    __shared__ float c_tile[64][32];
    const int tid = threadIdx.x;
    const int b  = blockIdx.x >> 4;
    const int i0 = (blockIdx.x & 15) << 6;

    if (!uniform && tid < 64) {
        const float* lg = logits + ((size_t)b * N_IN + i0 + tid) * NC;
        float e[NC];
        float mx = -1e30f;
        for (int n = 0; n < NC; ++n) { e[n] = lg[n]; mx = fmaxf(mx, e[n]); }
        float ssum = 0.f;
        for (int n = 0; n < NC; ++n) { float t = expf(e[n] - mx); e[n] = t; ssum += t; }
        float inv = 1.f / ssum;
        for (int n = 0; n < NC; ++n) c_tile[tid][n] = e[n] * inv;
    }
    __syncthreads();

    float acc[8] = {};
    const int nIdx = tid >> 3;   // z = tid*8 .. tid*8+7 all share n = tid>>3
    const unsigned short* base = u_hat + ((size_t)b * N_IN + i0) * 2048 + tid * 8;
    for (int il = 0; il < 64; ++il) {
        u16x8 v = *(const u16x8*)(base + (size_t)il * 2048);
        float c = uniform ? 0.03125f : c_tile[il][nIdx];
        for (int e2 = 0; e2 < 8; ++e2) acc[e2] += c * bf2f(v[e2]);
    }
    float* sp = s + (size_t)b * 2048 + tid * 8;
    for (int e2 = 0; e2 < 8; ++e2) atomicAdd(&sp[e2], acc[e2]);
}

// ---------------------------------------------------------------------------
// squash: out[row][d] = s[row][d] / sqrt(sum_d s^2 + eps)
// Writes fp32 to outs (ws) and, on last iteration, fp32 to d_out.
// ---------------------------------------------------------------------------
__global__ __launch_bounds__(256) void squash_kernel(const float* __restrict__ s,
                                                     float* __restrict__ outs,
                                                     float* __restrict__ out_f) {
    const int tid  = threadIdx.x;
    const int row  = blockIdx.x * 4 + (tid >> 6);
    const int lane = tid & 63;
    float v  = s[(size_t)row * 64 + lane];
    float sq = v * v;
    for (int off = 32; off; off >>= 1) sq += __shfl_xor(sq, off);
    float r = 1.0f / sqrtf(sq + 1e-7f);
    float o = v * r;
    outs[(size_t)row * 64 + lane] = o;
    if (out_f) out_f[(size_t)row * 64 + lane] = o;
}

// ---------------------------------------------------------------------------
// logits: logits[b][i][n] = sum_d outs[b][n][d] * u_hat[b,i,n*64+d]
// ---------------------------------------------------------------------------
__global__ __launch_bounds__(256) void logits_kernel(const unsigned short* __restrict__ u_hat,
                                                     const float* __restrict__ outs,
                                                     float* __restrict__ logits) {
    __shared__ float o[NC * 65];   // pad 64->65 to break 32-way bank aliasing
    const int tid = threadIdx.x;
    const int b  = blockIdx.x >> 7;
    const int i0 = (blockIdx.x & 127) << 3;
    for (int t = tid; t < 2048; t += 256)
        o[(t >> 6) * 65 + (t & 63)] = outs[(size_t)b * 2048 + t];
    __syncthreads();
    const int n  = tid & 31;
    const int il = tid >> 5;
    const unsigned short* row = u_hat + ((size_t)(b * N_IN + i0 + il)) * 2048 + n * 64;
    const float* on = &o[n * 65];
    float dot = 0.f;
    for (int jj = 0; jj < 8; ++jj) {
        u16x8 v = *(const u16x8*)(row + jj * 8);
        for (int e2 = 0; e2 < 8; ++e2) dot += on[jj * 8 + e2] * bf2f(v[e2]);
    }
    logits[((size_t)b * N_IN + i0 + il) * NC + n] = dot;
}

// ---------------------------------------------------------------------------
extern "C" void kernel_launch(void* const* d_in, const int* in_sizes, int n_in,
                              void* d_out, int out_size, void* d_ws, size_t ws_size,
                              hipStream_t stream) {
    (void)in_sizes; (void)n_in; (void)out_size; (void)ws_size;
    const float* u_vecs_f = (const float*)d_in[0];   // fp32 [65536][512]
    const float* W_f      = (const float*)d_in[1];   // fp32 [512][2048]
    float* out            = (float*)d_out;           // fp32 [64][32][64]

    uint8_t* ws = (uint8_t*)d_ws;
    const size_t UHAT_B = (size_t)M_TOT * N_TOT * 2;          // 256 MiB
    const size_t WT_B   = (size_t)N_TOT * K_TOT * 2;          // 2 MiB
    const size_t S_B    = (size_t)B_SZ * NC * DC * 4;         // 512 KiB
    const size_t LG_B   = (size_t)B_SZ * N_IN * NC * 4;       // 8 MiB
    unsigned short* u_hat = (unsigned short*)ws;
    unsigned short* Wt    = (unsigned short*)(ws + UHAT_B);
    float* s      = (float*)(ws + UHAT_B + WT_B);
    float* outs   = (float*)(ws + UHAT_B + WT_B + S_B);
    float* logits = (float*)(ws + UHAT_B + WT_B + 2 * S_B);
    unsigned short* A_bf  = (unsigned short*)(ws + UHAT_B + WT_B + 2 * S_B + LG_B); // 64 MiB

    convert_a<<<(size_t)M_TOT * K_TOT / (256 * 8), 256, 0, stream>>>(u_vecs_f, A_bf);
    transpose_w<<<dim3(64, 16), 256, 0, stream>>>(W_f, Wt);
    gemm_kernel<<<dim3(512, 16), 256, 0, stream>>>(A_bf, Wt, u_hat);

    for (int it = 0; it < 3; ++it) {
        hipMemsetAsync(s, 0, S_B, stream);
        accum_kernel<<<B_SZ * 16, 256, 0, stream>>>(u_hat, logits, s, it == 0 ? 1 : 0);
        squash_kernel<<<B_SZ * NC / 4, 256, 0, stream>>>(s, outs, it == 2 ? out : nullptr);
        if (it < 2)
            logits_kernel<<<B_SZ * 128, 256, 0, stream>>>(u_hat, outs, logits);
    }
}

// Round 4
// 574.463 us; speedup vs baseline: 1.3661x; 1.3661x over previous
//
#include <hip/hip_runtime.h>
#include <hip/hip_bf16.h>

// Problem constants
#define B_SZ   64
#define N_IN   1024
#define D_IN   512
#define NC     32
#define DC     64
#define M_TOT  (B_SZ * N_IN)       // 65536
#define N_TOT  (NC * DC)           // 2048
#define K_TOT  D_IN                // 512

typedef __bf16 bf16x8 __attribute__((ext_vector_type(8)));
typedef float  f32x4  __attribute__((ext_vector_type(4)));
typedef unsigned short u16x8 __attribute__((ext_vector_type(8)));

__device__ __forceinline__ float bf2f(unsigned short u) {
    unsigned x = ((unsigned)u) << 16;
    return __builtin_bit_cast(float, x);
}
__device__ __forceinline__ unsigned short f2bf(float f) {
    unsigned x = __builtin_bit_cast(unsigned, f);
    unsigned r = (x + 0x7fffu + ((x >> 16) & 1u)) >> 16;   // RNE
    return (unsigned short)r;
}

#define ASYNC_LDS16(g, l) __builtin_amdgcn_global_load_lds( \
    (const __attribute__((address_space(1))) void*)(g),     \
    (__attribute__((address_space(3))) void*)(l), 16, 0, 0)

// ---------------------------------------------------------------------------
// A convert: fp32 [65536][512] -> bf16 (ushort) same layout.
// ---------------------------------------------------------------------------
__global__ __launch_bounds__(256) void convert_a(const float* __restrict__ in,
                                                 unsigned short* __restrict__ out) {
    size_t idx = ((size_t)blockIdx.x * 256 + threadIdx.x) * 8;
    float4 v0 = *(const float4*)(in + idx);
    float4 v1 = *(const float4*)(in + idx + 4);
    u16x8 r;
    r[0] = f2bf(v0.x); r[1] = f2bf(v0.y); r[2] = f2bf(v0.z); r[3] = f2bf(v0.w);
    r[4] = f2bf(v1.x); r[5] = f2bf(v1.y); r[6] = f2bf(v1.z); r[7] = f2bf(v1.w);
    *(u16x8*)(out + idx) = r;
}

// ---------------------------------------------------------------------------
// W transpose+convert: W fp32 [512][2048] -> Wt bf16 [2048][512]
// ---------------------------------------------------------------------------
__global__ __launch_bounds__(256) void transpose_w(const float* __restrict__ W,
                                                   unsigned short* __restrict__ Wt) {
    __shared__ unsigned short tile[32][33];
    const int n0 = blockIdx.x * 32;   // over N=2048
    const int k0 = blockIdx.y * 32;   // over K=512
    const int c  = threadIdx.x & 31;
    const int r4 = threadIdx.x >> 5;  // 0..7
    for (int it = 0; it < 4; ++it) {
        int r = it * 8 + r4;
        tile[r][c] = f2bf(W[(size_t)(k0 + r) * 2048 + n0 + c]);
    }
    __syncthreads();
    for (int it = 0; it < 4; ++it) {
        int r = it * 8 + r4;
        Wt[(size_t)(n0 + r) * 512 + k0 + c] = tile[c][r];
    }
}

// ---------------------------------------------------------------------------
// GEMM: u_hat[M=65536][N=2048] = A[M][K=512] * Wt[N][K]^T  (bf16 in, bf16 out)
// 128x128 tile, 4 waves (2x2 of 64x64), BK=64, 16x16x32 bf16 MFMA.
// 1D grid with XCD-aware swizzle: each XCD (id&7, assuming round-robin
// dispatch) owns a contiguous M range and iterates all 16 N-blocks per
// M-strip, so the A strip (128 KB) + full Wt (2 MB) stay L2-resident.
// ---------------------------------------------------------------------------
__global__ __launch_bounds__(256, 2) void gemm_kernel(const unsigned short* __restrict__ A,
                                                      const unsigned short* __restrict__ Bt,
                                                      unsigned short* __restrict__ Chat) {
    __shared__ unsigned short As[128 * 64];
    __shared__ unsigned short Bs[128 * 64];
    const int tid  = threadIdx.x;
    const int wid  = tid >> 6;
    const int lane = tid & 63;
    const int id   = blockIdx.x;          // 8192 blocks
    const int xcd  = id & 7;
    const int seq  = id >> 3;             // 0..1023
    const int n0   = (seq & 15) * 128;
    const int m0   = ((xcd << 6) | (seq >> 4)) * 128;
    const int wrow = (wid >> 1) * 64;
    const int wcol = (wid & 1) * 64;

    const int lr = lane >> 3;                      // row within wave chunk (0..7)
    const int lc = ((lane & 7) ^ (lr & 7)) * 8;    // swizzled global k-chunk offset

    f32x4 acc[4][4] = {};

    const int quad = lane >> 4;
    const int l16  = lane & 15;

    for (int kt = 0; kt < 8; ++kt) {
        const int k0 = kt * 64;
        for (int iss = 0; iss < 4; ++iss) {
            const int rowbase = iss * 32 + wid * 8;
            const unsigned short* ga = A  + (size_t)(m0 + rowbase + lr) * 512 + k0 + lc;
            ASYNC_LDS16(ga, &As[rowbase * 64]);
            const unsigned short* gb = Bt + (size_t)(n0 + rowbase + lr) * 512 + k0 + lc;
            ASYNC_LDS16(gb, &Bs[rowbase * 64]);
        }
        __syncthreads();
        for (int kc = 0; kc < 2; ++kc) {
            const int C = kc * 4 + quad;           // global 16B-chunk index within BK
            bf16x8 af[4], bfr[4];
            for (int i = 0; i < 4; ++i) {
                int R = wrow + i * 16 + l16;
                af[i] = *(const bf16x8*)&As[R * 64 + ((C ^ (R & 7)) << 3)];
            }
            for (int j = 0; j < 4; ++j) {
                int R = wcol + j * 16 + l16;
                bfr[j] = *(const bf16x8*)&Bs[R * 64 + ((C ^ (R & 7)) << 3)];
            }
            for (int i = 0; i < 4; ++i)
                for (int j = 0; j < 4; ++j)
                    acc[i][j] = __builtin_amdgcn_mfma_f32_16x16x32_bf16(af[i], bfr[j], acc[i][j], 0, 0, 0);
        }
        __syncthreads();
    }

    // epilogue: D row = quad*4 + r, col = lane&15
    const int cm = quad * 4;
    for (int i = 0; i < 4; ++i)
        for (int j = 0; j < 4; ++j) {
            size_t base = (size_t)(m0 + wrow + i * 16 + cm) * 2048 + (n0 + wcol + j * 16 + l16);
            for (int r = 0; r < 4; ++r)
                Chat[base + (size_t)r * 2048] = f2bf(acc[i][j][r]);
        }
}

// ---------------------------------------------------------------------------
// rowsum: Arow[b][k] = sum_i A_bf[b,i,k]  (fp32 accum over 1024 bf16 rows)
// grid 512: 8 blocks per b, 128 rows each; atomics into Arow (memset first).
// ---------------------------------------------------------------------------
__global__ __launch_bounds__(256) void rowsum_kernel(const unsigned short* __restrict__ A,
                                                     float* __restrict__ Arow) {
    const int tid = threadIdx.x;
    const int b  = blockIdx.x >> 3;
    const int r0 = (blockIdx.x & 7) << 7;   // 128 rows
    const unsigned short* p = A + ((size_t)b * N_IN + r0) * 512 + tid * 2;
    float a0 = 0.f, a1 = 0.f;
    for (int r = 0; r < 128; ++r) {
        unsigned u = *(const unsigned*)(p + (size_t)r * 512);
        a0 += bf2f((unsigned short)(u & 0xffffu));
        a1 += bf2f((unsigned short)(u >> 16));
    }
    atomicAdd(&Arow[b * 512 + tid * 2], a0);
    atomicAdd(&Arow[b * 512 + tid * 2 + 1], a1);
}

// ---------------------------------------------------------------------------
// s0: s[b][z] = (1/32) * sum_k Arow[b][k] * W[k][z]   (fp32, W fp32 direct)
// Replaces the uniform-c iteration-0 accumulation (saves a 256 MB pass).
// ---------------------------------------------------------------------------
__global__ __launch_bounds__(256) void s0_kernel(const float* __restrict__ Arow,
                                                 const float* __restrict__ W,
                                                 float* __restrict__ s) {
    __shared__ float ar[512];
    const int tid = threadIdx.x;
    const int b  = blockIdx.x >> 3;
    const int z0 = (blockIdx.x & 7) << 8;
    ar[tid]       = Arow[b * 512 + tid];
    ar[tid + 256] = Arow[b * 512 + 256 + tid];
    __syncthreads();
    const int z = z0 + tid;
    float acc = 0.f;
    for (int k = 0; k < 512; ++k) acc += ar[k] * W[(size_t)k * 2048 + z];
    s[(size_t)b * 2048 + z] = acc * 0.03125f;
}

// ---------------------------------------------------------------------------
// fused routing: per row i, logits[n] = outs[b,n,:]·u_hat[b,i,n*64:+64],
// c = softmax_n(logits), s[b,n,d] += c[n]*u_hat (atomic). One u_hat pass
// serves both the logits einsum and the next accumulation.
// Block = (b, 64 rows). Thread owns z = tid*8..+7 (n = tid>>3). Rows staged
// 16 at a time in registers; dot reduced over the 8-lane d-group via shuffle.
// ---------------------------------------------------------------------------
__global__ __launch_bounds__(256) void fused_routing(const unsigned short* __restrict__ u_hat,
                                                     const float* __restrict__ outs,
                                                     float* __restrict__ s) {
    __shared__ float l_lds[64][33];
    const int tid = threadIdx.x;
    const int b  = blockIdx.x >> 4;
    const int i0 = (blockIdx.x & 15) << 6;
    const int n  = tid >> 3;

    float o_reg[8];
    {
        float4 a = *(const float4*)(outs + (size_t)b * 2048 + tid * 8);
        float4 c4 = *(const float4*)(outs + (size_t)b * 2048 + tid * 8 + 4);
        o_reg[0] = a.x;  o_reg[1] = a.y;  o_reg[2] = a.z;  o_reg[3] = a.w;
        o_reg[4] = c4.x; o_reg[5] = c4.y; o_reg[6] = c4.z; o_reg[7] = c4.w;
    }

    float acc[8] = {};
    const unsigned short* base = u_hat + ((size_t)b * N_IN + i0) * 2048 + tid * 8;

    for (int sub = 0; sub < 4; ++sub) {
        u16x8 v[16];
        for (int r = 0; r < 16; ++r)
            v[r] = *(const u16x8*)(base + (size_t)(sub * 16 + r) * 2048);
        // logits via 8-lane shuffle reduction (lanes tid&7 share capsule n)
        for (int r = 0; r < 16; ++r) {
            float p = 0.f;
            for (int e = 0; e < 8; ++e) p += o_reg[e] * bf2f(v[r][e]);
            p += __shfl_xor(p, 1);
            p += __shfl_xor(p, 2);
            p += __shfl_xor(p, 4);
            if ((tid & 7) == 0) l_lds[sub * 16 + r][n] = p;
        }
        __syncthreads();
        // softmax over the 32 capsules, one thread per row
        if (tid < 16) {
            float* row = l_lds[sub * 16 + tid];
            float mx = row[0];
            for (int k = 1; k < NC; ++k) mx = fmaxf(mx, row[k]);
            float ssum = 0.f;
            for (int k = 0; k < NC; ++k) { float t = __expf(row[k] - mx); row[k] = t; ssum += t; }
            float inv = 1.f / ssum;
            for (int k = 0; k < NC; ++k) row[k] *= inv;
        }
        __syncthreads();
        // accumulate c * u_hat into registers
        for (int r = 0; r < 16; ++r) {
            float c = l_lds[sub * 16 + r][n];
            for (int e = 0; e < 8; ++e) acc[e] += c * bf2f(v[r][e]);
        }
    }

    float* sp = s + (size_t)b * 2048 + tid * 8;
    for (int e = 0; e < 8; ++e) atomicAdd(&sp[e], acc[e]);
}

// ---------------------------------------------------------------------------
// squash: out[row][d] = s[row][d] / sqrt(sum_d s^2 + eps)
// ---------------------------------------------------------------------------
__global__ __launch_bounds__(256) void squash_kernel(const float* __restrict__ s,
                                                     float* __restrict__ outs,
                                                     float* __restrict__ out_f) {
    const int tid  = threadIdx.x;
    const int row  = blockIdx.x * 4 + (tid >> 6);
    const int lane = tid & 63;
    float v  = s[(size_t)row * 64 + lane];
    float sq = v * v;
    for (int off = 32; off; off >>= 1) sq += __shfl_xor(sq, off);
    float r = 1.0f / sqrtf(sq + 1e-7f);
    float o = v * r;
    outs[(size_t)row * 64 + lane] = o;
    if (out_f) out_f[(size_t)row * 64 + lane] = o;
}

// ---------------------------------------------------------------------------
extern "C" void kernel_launch(void* const* d_in, const int* in_sizes, int n_in,
                              void* d_out, int out_size, void* d_ws, size_t ws_size,
                              hipStream_t stream) {
    (void)in_sizes; (void)n_in; (void)out_size; (void)ws_size;
    const float* u_vecs_f = (const float*)d_in[0];   // fp32 [65536][512]
    const float* W_f      = (const float*)d_in[1];   // fp32 [512][2048]
    float* out            = (float*)d_out;           // fp32 [64][32][64]

    uint8_t* ws = (uint8_t*)d_ws;
    const size_t UHAT_B = (size_t)M_TOT * N_TOT * 2;          // 256 MiB
    const size_t WT_B   = (size_t)N_TOT * K_TOT * 2;          // 2 MiB
    const size_t S_B    = (size_t)B_SZ * NC * DC * 4;         // 512 KiB
    const size_t AROW_B = (size_t)B_SZ * K_TOT * 4;           // 128 KiB
    unsigned short* u_hat = (unsigned short*)ws;
    unsigned short* Wt    = (unsigned short*)(ws + UHAT_B);
    float* s      = (float*)(ws + UHAT_B + WT_B);
    float* outs   = (float*)(ws + UHAT_B + WT_B + S_B);
    float* Arow   = (float*)(ws + UHAT_B + WT_B + 2 * S_B);
    unsigned short* A_bf  = (unsigned short*)(ws + UHAT_B + WT_B + 2 * S_B + AROW_B); // 64 MiB

    convert_a<<<(size_t)M_TOT * K_TOT / (256 * 8), 256, 0, stream>>>(u_vecs_f, A_bf);
    transpose_w<<<dim3(64, 16), 256, 0, stream>>>(W_f, Wt);
    gemm_kernel<<<8192, 256, 0, stream>>>(A_bf, Wt, u_hat);

    // iteration 0: uniform c == rank-64 GEMM on row-sums (no u_hat pass)
    hipMemsetAsync(Arow, 0, AROW_B, stream);
    rowsum_kernel<<<512, 256, 0, stream>>>(A_bf, Arow);
    s0_kernel<<<512, 256, 0, stream>>>(Arow, W_f, s);
    squash_kernel<<<B_SZ * NC / 4, 256, 0, stream>>>(s, outs, nullptr);

    // iterations 1 and 2: fused logits+softmax+accum (one u_hat pass each)
    hipMemsetAsync(s, 0, S_B, stream);
    fused_routing<<<B_SZ * 16, 256, 0, stream>>>(u_hat, outs, s);
    squash_kernel<<<B_SZ * NC / 4, 256, 0, stream>>>(s, outs, nullptr);

    hipMemsetAsync(s, 0, S_B, stream);
    fused_routing<<<B_SZ * 16, 256, 0, stream>>>(u_hat, outs, s);
    squash_kernel<<<B_SZ * NC / 4, 256, 0, stream>>>(s, outs, out);
}